// Round 9
// baseline (83.394 us; speedup 1.0000x reference)
//
#include <hip/hip_runtime.h>
#include <hip/hip_bf16.h>

// DenseEnergyLoss on MI355X. N=4, K=21, H=W=128 -> OH=OW=64, P=4096.
// loss = 0.1*(-0.5)/(N*P) * sum_{n,p,q} exp(-0.5*max(|f_p-f_q|^2,0)) * gate_p * <seg_p, seg_q>
// Symmetrized: gate_p -> (gate_p+gate_q)/2; upper-triangular 128x128 tile-pairs,
// diag tiles weighted 0.5 (off-diag x2 folded).
// R9: prep parallelism fix. prep was 64 blocks x 256 thr (1/4 of CUs, ~90
// scattered loads/thread) and likely ~10-15us of the "fixed" overhead.
// Now 1024 blocks x 64 thr: one wave per (n,y) output row -> per k the wave
// reads two full contiguous 512B rows, spread over all CUs.
// energy_kernel / reduce_kernel byte-identical to R8 (single-variable exp).

constexpr int N_ = 4, K_ = 21, H_ = 128, W_ = 128, P_ = 4096;
constexpr int T_ = 128;                  // tile size (p and q)
constexpr int NT = P_ / T_;              // 32 tiles per dim
constexpr int NTRI = NT * (NT + 1) / 2;  // 528 upper-tri tile pairs per n
constexpr int NBLK = NTRI * N_;          // 2112 energy blocks
constexpr float INV_RGB = 1.0f / 15.0f;
constexpr float INV_XY = 1.0f / 40.0f;   // 1/(SIGMA_XY*SCALE)
constexpr float LOG2E = 1.4426950408889634f;
constexpr float NEG_HALF_LOG2E = -0.72134752044448170f;
constexpr float OUT_SCALE = -0.05f / 16384.0f; // 0.1 * -0.5 / (N*P)

typedef _Float16 half8 __attribute__((ext_vector_type(8)));
typedef float floatx4 __attribute__((ext_vector_type(4)));

// Workspace: comb (N*P*32 f16 = 1 MB), scal (N*P float2), partial (NBLK f32).

__global__ void __launch_bounds__(64) prep_kernel(
    const float* __restrict__ img, const float* __restrict__ seg,
    const float* __restrict__ roi, const float* __restrict__ lab,
    _Float16* __restrict__ comb, float2* __restrict__ scal) {
  int idx = blockIdx.x * 64 + threadIdx.x; // n*P + p ; one wave == one (n,y) row
  int n = idx >> 12;
  int p = idx & (P_ - 1);
  int y = p >> 6, x = p & 63;
  int iy = 2 * y, ix = 2 * x;
  const size_t hw = (size_t)H_ * W_;

  float r = roi[(size_t)n * hw + iy * W_ + ix];
  float lb = lab[(size_t)n * hw + iy * W_ + ix];
  bool unlabeled = ((int)lb == 255);

  const float* sb = seg + (size_t)n * K_ * hw + (size_t)iy * W_ + ix;
  _Float16 ch[32];
  float mx = -1e30f;
#pragma unroll
  for (int k = 0; k < K_; k++) {
    const float* s = sb + (size_t)k * hw;
    float v = 0.25f * (s[0] + s[1] + s[W_] + s[W_ + 1]); // bilinear @0.5 == 2x2 avg
    mx = fmaxf(mx, v);
    ch[k] = (_Float16)(v * r); // seg_m = seg_s * roi, rounded to f16
  }
  ch[21] = (_Float16)0.0f; ch[22] = (_Float16)0.0f; ch[23] = (_Float16)0.0f;

  const float* ib = img + (size_t)n * 3 * hw + (size_t)iy * W_ + ix;
  ch[24] = (_Float16)((float)x * INV_XY);
  ch[25] = (_Float16)((float)y * INV_XY);
  ch[26] = (_Float16)(ib[0] * INV_RGB);
  ch[27] = (_Float16)(ib[hw] * INV_RGB);
  ch[28] = (_Float16)(ib[2 * hw] * INV_RGB);
  ch[29] = (_Float16)0.0f; ch[30] = (_Float16)0.0f; ch[31] = (_Float16)0.0f;

  // cs from the ROUNDED features so diagonal d2 ~ 0 exactly.
  float sq = 0.0f;
#pragma unroll
  for (int j = 24; j < 29; j++) { float v = (float)ch[j]; sq = fmaf(v, v, sq); }

  float4* dst = (float4*)(comb + (size_t)idx * 32);
  const float4* src = (const float4*)ch;
#pragma unroll
  for (int j = 0; j < 4; j++) dst[j] = src[j];

  float g = unlabeled ? 1.0f : (r - mx);
  scal[idx] = make_float2(NEG_HALF_LOG2E * sq, fmaxf(g, 0.0f));
}

__global__ void __launch_bounds__(256) energy_kernel(
    const _Float16* __restrict__ comb, const float2* __restrict__ scal,
    float* __restrict__ partial) {
  // Decode upper-triangular tile pair (pb <= qb) from blockIdx.x in [0, 528).
  int t = blockIdx.x;
  int pb = 0;
  while (t >= NT - pb) { t -= NT - pb; pb++; }
  int qb = pb + t;
  int n = blockIdx.y;
  int tid = threadIdx.x;
  int lane = tid & 63, wave = tid >> 6;
  int m = lane & 15, quad = lane >> 4;

  const _Float16* combn = comb + (size_t)n * P_ * 32;
  const float2* scaln = scal + (size_t)n * P_;
  const half8 zfrag = {};

  // ---- Preload EVERYTHING into registers (no memory ops in compute loop) ----
  half8 acomb[2], aseg0[2];
#pragma unroll
  for (int s = 0; s < 2; s++) {
    int prow = pb * T_ + (2 * wave + s) * 16 + m;
    acomb[s] = *(const half8*)(combn + (size_t)prow * 32 + quad * 8);
    aseg0[s] = (quad == 3) ? zfrag : acomb[s]; // kill feat channels for G
  }
  half8 bcomb[8];
  float2 qsc[8];
#pragma unroll
  for (int qs = 0; qs < 8; qs++) {
    int qrow = qb * T_ + qs * 16 + m;
    bcomb[qs] = *(const half8*)(combn + (size_t)qrow * 32 + quad * 8);
    qsc[qs] = scaln[qb * T_ + qs * 16 + m];
  }
  float cspv[2][4], gpv[2][4];
#pragma unroll
  for (int s = 0; s < 2; s++)
#pragma unroll
    for (int r = 0; r < 4; r++) {
      float2 tpr = scaln[pb * T_ + (2 * wave + s) * 16 + quad * 4 + r];
      cspv[s][r] = tpr.x; gpv[s][r] = tpr.y;
    }

  // ---- Pure compute loop, FULLY unrolled: all indices compile-time ----
  float acc = 0.0f;
#pragma unroll
  for (int qs = 0; qs < 8; qs++) {
#pragma unroll
    for (int s = 0; s < 2; s++) {
      floatx4 C1 = {0.0f, 0.0f, 0.0f, 0.0f};
      floatx4 G = {0.0f, 0.0f, 0.0f, 0.0f};
      C1 = __builtin_amdgcn_mfma_f32_16x16x32_f16(acomb[s], bcomb[qs], C1, 0, 0, 0);
      G = __builtin_amdgcn_mfma_f32_16x16x32_f16(aseg0[s], bcomb[qs], G, 0, 0, 0);
#pragma unroll
      for (int r = 0; r < 4; r++) {
        float dot = C1[r] - G[r];
        float arg = fmaf(LOG2E, dot, cspv[s][r] + qsc[qs].x);
        float A = __builtin_amdgcn_exp2f(arg);
        A = fminf(A, 1.0f);
        acc = fmaf(A * G[r], gpv[s][r] + qsc[qs].y, acc);
      }
    }
  }

  // Reduce within block; store partial to a distinct address (no atomics).
#pragma unroll
  for (int off = 32; off > 0; off >>= 1) acc += __shfl_down(acc, off, 64);
  __shared__ float wsum[4];
  if (lane == 0) wsum[wave] = acc;
  __syncthreads();
  if (tid == 0) {
    float s = (wsum[0] + wsum[1]) + (wsum[2] + wsum[3]);
    float wb = (pb == qb) ? 0.5f : 1.0f;
    partial[blockIdx.y * NTRI + blockIdx.x] = s * wb;
  }
}

__global__ void __launch_bounds__(256) reduce_kernel(
    const float* __restrict__ partial, float* __restrict__ out) {
  int tid = threadIdx.x;
  float acc = 0.0f;
  for (int i = tid; i < NBLK; i += 256) acc += partial[i];
#pragma unroll
  for (int off = 32; off > 0; off >>= 1) acc += __shfl_down(acc, off, 64);
  __shared__ float wsum[4];
  int lane = tid & 63, wave = tid >> 6;
  if (lane == 0) wsum[wave] = acc;
  __syncthreads();
  if (tid == 0) {
    float s = (wsum[0] + wsum[1]) + (wsum[2] + wsum[3]);
    out[0] = s * OUT_SCALE;
  }
}

extern "C" void kernel_launch(void* const* d_in, const int* in_sizes, int n_in,
                              void* d_out, int out_size, void* d_ws, size_t ws_size,
                              hipStream_t stream) {
  const float* images = (const float*)d_in[0];
  const float* segs = (const float*)d_in[1];
  const float* rois = (const float*)d_in[2];
  const float* labels = (const float*)d_in[3];
  float* out = (float*)d_out;

  char* ws = (char*)d_ws;
  _Float16* comb = (_Float16*)ws;                                  // 1 MB
  float2* scal = (float2*)(ws + (size_t)N_ * P_ * 32 * 2);         // 128 KB
  float* partial = (float*)(ws + (size_t)N_ * P_ * 32 * 2 +
                            (size_t)N_ * P_ * sizeof(float2));     // 8.25 KB

  prep_kernel<<<dim3(N_ * P_ / 64), dim3(64), 0, stream>>>(
      images, segs, rois, labels, comb, scal);
  energy_kernel<<<dim3(NTRI, N_), dim3(256), 0, stream>>>(comb, scal, partial);
  reduce_kernel<<<dim3(1), dim3(256), 0, stream>>>(partial, out);
}

// Round 10
// 80.531 us; speedup vs baseline: 1.0356x; 1.0356x over previous
//
#include <hip/hip_runtime.h>
#include <hip/hip_bf16.h>

// DenseEnergyLoss on MI355X. N=4, K=21, H=W=128 -> OH=OW=64, P=4096.
// loss = 0.1*(-0.5)/(N*P) * sum_{n,p,q} exp(-0.5*max(|f_p-f_q|^2,0)) * gate_p * <seg_p, seg_q>
// Symmetrized: gate_p -> (gate_p+gate_q)/2; upper-triangular 128x128 tile-pairs,
// diag 0.5 / off-diag 1.0 (x2 folded).
// R10: epilogue cut 8 -> 6 instr/pair by folding the affine part of arg into
// the MFMA. Features pre-scaled by sqrt(log2e); ch29 = cs(f16), ch30 = 1.0.
// B-side fragments patched in registers (quad3: j5<-1, j6<-cs, j7<-0) so
//   C1 = acomb x bcomb = G + log2e*fp.fq + csp + csq ;  arg = C1 - G.
// G = aseg0 x bcomb (quad3 zeroed on A side; ch21..23 are stored zeros).
// Epilogue: sub, exp2, min, mul, add, fma. min-clamp also bounds f16-cs error.
// MFMA layouts (HW-verified m89/m120): A/B point=lane&15, k=(lane>>4)*8+j;
// C/D col=lane&15, row=(lane>>4)*4+reg.

constexpr int N_ = 4, K_ = 21, H_ = 128, W_ = 128, P_ = 4096;
constexpr int T_ = 128;                  // tile size (p and q)
constexpr int NT = P_ / T_;              // 32 tiles per dim
constexpr int NTRI = NT * (NT + 1) / 2;  // 528 upper-tri tile pairs per n
constexpr int NBLK = NTRI * N_;          // 2112 energy blocks
constexpr float INV_RGB = 1.0f / 15.0f;
constexpr float INV_XY = 1.0f / 40.0f;   // 1/(SIGMA_XY*SCALE)
constexpr float SQRT_LOG2E = 1.2011224087864498f; // sqrt(log2(e))
constexpr float OUT_SCALE = -0.05f / 16384.0f;    // 0.1 * -0.5 / (N*P)

typedef _Float16 half8 __attribute__((ext_vector_type(8)));
typedef float floatx4 __attribute__((ext_vector_type(4)));

// comb row (32 f16): ch0..20 seg_m, ch21..23 = 0, ch24..28 = f*sqrt(log2e),
// ch29 = cs = -0.5*sum(ch24..28^2) (f16), ch30 = 1.0, ch31 = 0.
// gate  (N*P f32) separate array.

__global__ void __launch_bounds__(64) prep_kernel(
    const float* __restrict__ img, const float* __restrict__ seg,
    const float* __restrict__ roi, const float* __restrict__ lab,
    _Float16* __restrict__ comb, float* __restrict__ gate) {
  int idx = blockIdx.x * 64 + threadIdx.x; // n*P + p ; one wave == one (n,y) row
  int n = idx >> 12;
  int p = idx & (P_ - 1);
  int y = p >> 6, x = p & 63;
  int iy = 2 * y, ix = 2 * x;
  const size_t hw = (size_t)H_ * W_;

  float r = roi[(size_t)n * hw + iy * W_ + ix];
  float lb = lab[(size_t)n * hw + iy * W_ + ix];
  bool unlabeled = ((int)lb == 255);

  const float* sb = seg + (size_t)n * K_ * hw + (size_t)iy * W_ + ix;
  _Float16 ch[32];
  float mx = -1e30f;
#pragma unroll
  for (int k = 0; k < K_; k++) {
    const float* s = sb + (size_t)k * hw;
    float v = 0.25f * (s[0] + s[1] + s[W_] + s[W_ + 1]); // bilinear @0.5 == 2x2 avg
    mx = fmaxf(mx, v);
    ch[k] = (_Float16)(v * r); // seg_m = seg_s * roi, rounded to f16
  }
  ch[21] = (_Float16)0.0f; ch[22] = (_Float16)0.0f; ch[23] = (_Float16)0.0f;

  const float* ib = img + (size_t)n * 3 * hw + (size_t)iy * W_ + ix;
  ch[24] = (_Float16)((float)x * INV_XY * SQRT_LOG2E);
  ch[25] = (_Float16)((float)y * INV_XY * SQRT_LOG2E);
  ch[26] = (_Float16)(ib[0] * INV_RGB * SQRT_LOG2E);
  ch[27] = (_Float16)(ib[hw] * INV_RGB * SQRT_LOG2E);
  ch[28] = (_Float16)(ib[2 * hw] * INV_RGB * SQRT_LOG2E);

  // cs from the ROUNDED, pre-scaled channels: arg_diag = sum(ch^2) + 2*cs ~ 0.
  float sq = 0.0f;
#pragma unroll
  for (int j = 24; j < 29; j++) { float v = (float)ch[j]; sq = fmaf(v, v, sq); }
  ch[29] = (_Float16)(-0.5f * sq);
  ch[30] = (_Float16)1.0f;
  ch[31] = (_Float16)0.0f;

  float4* dst = (float4*)(comb + (size_t)idx * 32);
  const float4* src = (const float4*)ch;
#pragma unroll
  for (int j = 0; j < 4; j++) dst[j] = src[j];

  float g = unlabeled ? 1.0f : (r - mx);
  gate[idx] = fmaxf(g, 0.0f);
}

__global__ void __launch_bounds__(256) energy_kernel(
    const _Float16* __restrict__ comb, const float* __restrict__ gate,
    float* __restrict__ partial) {
  // Decode upper-triangular tile pair (pb <= qb) from blockIdx.x in [0, 528).
  int t = blockIdx.x;
  int pb = 0;
  while (t >= NT - pb) { t -= NT - pb; pb++; }
  int qb = pb + t;
  int n = blockIdx.y;
  int tid = threadIdx.x;
  int lane = tid & 63, wave = tid >> 6;
  int m = lane & 15, quad = lane >> 4;

  const _Float16* combn = comb + (size_t)n * P_ * 32;
  const float* gaten = gate + (size_t)n * P_;
  const half8 zfrag = {};

  // ---- Preload EVERYTHING into registers (no memory ops in compute loop) ----
  half8 acomb[2], aseg0[2];
#pragma unroll
  for (int s = 0; s < 2; s++) {
    int prow = pb * T_ + (2 * wave + s) * 16 + m;
    acomb[s] = *(const half8*)(combn + (size_t)prow * 32 + quad * 8);
    aseg0[s] = (quad == 3) ? zfrag : acomb[s]; // kill feat/cs channels for G
  }
  half8 bcomb[8];
  float gqv[8];
#pragma unroll
  for (int qs = 0; qs < 8; qs++) {
    int qrow = qb * T_ + qs * 16 + m;
    half8 b = *(const half8*)(combn + (size_t)qrow * 32 + quad * 8);
    if (quad == 3) {
      _Float16 cs = b[5];           // stored ch29 = cs(q)
      b[5] = (_Float16)1.0f;        // B ch29 pairs with A's csp
      b[6] = cs;                    // B ch30 = cs(q) pairs with A's 1.0
      b[7] = (_Float16)0.0f;
    }
    bcomb[qs] = b;
    gqv[qs] = gaten[qb * T_ + qs * 16 + m];
  }
  float gpv[2][4];
#pragma unroll
  for (int s = 0; s < 2; s++)
#pragma unroll
    for (int r = 0; r < 4; r++)
      gpv[s][r] = gaten[pb * T_ + (2 * wave + s) * 16 + quad * 4 + r];

  // ---- Pure compute loop, FULLY unrolled: all indices compile-time ----
  float acc = 0.0f;
#pragma unroll
  for (int qs = 0; qs < 8; qs++) {
#pragma unroll
    for (int s = 0; s < 2; s++) {
      floatx4 C1 = {0.0f, 0.0f, 0.0f, 0.0f};
      floatx4 G = {0.0f, 0.0f, 0.0f, 0.0f};
      C1 = __builtin_amdgcn_mfma_f32_16x16x32_f16(acomb[s], bcomb[qs], C1, 0, 0, 0);
      G = __builtin_amdgcn_mfma_f32_16x16x32_f16(aseg0[s], bcomb[qs], G, 0, 0, 0);
#pragma unroll
      for (int r = 0; r < 4; r++) {
        float arg = C1[r] - G[r];              // = log2e*fp.fq + csp + csq
        float A = __builtin_amdgcn_exp2f(arg);
        A = fminf(A, 1.0f);
        acc = fmaf(A * G[r], gpv[s][r] + gqv[qs], acc);
      }
    }
  }

  // Reduce within block; store partial to a distinct address (no atomics).
#pragma unroll
  for (int off = 32; off > 0; off >>= 1) acc += __shfl_down(acc, off, 64);
  __shared__ float wsum[4];
  if (lane == 0) wsum[wave] = acc;
  __syncthreads();
  if (tid == 0) {
    float s = (wsum[0] + wsum[1]) + (wsum[2] + wsum[3]);
    float wb = (pb == qb) ? 0.5f : 1.0f;
    partial[blockIdx.y * NTRI + blockIdx.x] = s * wb;
  }
}

__global__ void __launch_bounds__(256) reduce_kernel(
    const float* __restrict__ partial, float* __restrict__ out) {
  int tid = threadIdx.x;
  float acc = 0.0f;
  for (int i = tid; i < NBLK; i += 256) acc += partial[i];
#pragma unroll
  for (int off = 32; off > 0; off >>= 1) acc += __shfl_down(acc, off, 64);
  __shared__ float wsum[4];
  int lane = tid & 63, wave = tid >> 6;
  if (lane == 0) wsum[wave] = acc;
  __syncthreads();
  if (tid == 0) {
    float s = (wsum[0] + wsum[1]) + (wsum[2] + wsum[3]);
    out[0] = s * OUT_SCALE;
  }
}

extern "C" void kernel_launch(void* const* d_in, const int* in_sizes, int n_in,
                              void* d_out, int out_size, void* d_ws, size_t ws_size,
                              hipStream_t stream) {
  const float* images = (const float*)d_in[0];
  const float* segs = (const float*)d_in[1];
  const float* rois = (const float*)d_in[2];
  const float* labels = (const float*)d_in[3];
  float* out = (float*)d_out;

  char* ws = (char*)d_ws;
  _Float16* comb = (_Float16*)ws;                                  // 1 MB
  float* gate = (float*)(ws + (size_t)N_ * P_ * 32 * 2);           // 64 KB
  float* partial = (float*)(ws + (size_t)N_ * P_ * 32 * 2 +
                            (size_t)N_ * P_ * sizeof(float));      // 8.25 KB

  prep_kernel<<<dim3(N_ * P_ / 64), dim3(64), 0, stream>>>(
      images, segs, rois, labels, comb, gate);
  energy_kernel<<<dim3(NTRI, N_), dim3(256), 0, stream>>>(comb, gate, partial);
  reduce_kernel<<<dim3(1), dim3(256), 0, stream>>>(partial, out);
}

// Round 11
// 80.128 us; speedup vs baseline: 1.0408x; 1.0050x over previous
//
#include <hip/hip_runtime.h>
#include <hip/hip_bf16.h>

// DenseEnergyLoss on MI355X. N=4, K=21, H=W=128 -> OH=OW=64, P=4096.
// loss = 0.1*(-0.5)/(N*P) * sum_{n,p,q} exp(-0.5*max(|f_p-f_q|^2,0)) * gate_p * <seg_p, seg_q>
// Symmetrized: gate_p -> (gate_p+gate_q)/2; upper-triangular 128x128 tile-pairs,
// diag 0.5 / off-diag 1.0 (x2 folded).
// R11: occupancy fix. Attribution (R7 direct measure: non-energy = 51.8us) puts
// E_R10 at ~28us vs a 5-9us issue floor -> latency-bound. Suspect: full preload
// of 8 B-fragments + pipelined C1/G pushed VGPR > 128 -> 2 waves/SIMD (m69
// cliff). Fix: __launch_bounds__(256,4) caps VGPR at 128 (>=4 waves/SIMD) and
// B-fragments/gq are STREAMED inside the fully-unrolled qs loop (compile-time
// indices only -- R7 lesson) so the cap is honored without spills.
// comb row (32 f16): ch0..20 seg_m, ch21..23=0, ch24..28 = f*sqrt(log2e),
// ch29 = cs(f16), ch30 = 1.0, ch31 = 0.  B quad3 patched (j5<-1, j6<-cs, j7<-0):
//   C1 = acomb x bcomb = G + log2e*fp.fq + csp + csq ; arg = C1 - G.
// MFMA layouts (HW-verified m89/m120): A/B point=lane&15, k=(lane>>4)*8+j;
// C/D col=lane&15, row=(lane>>4)*4+reg.

constexpr int N_ = 4, K_ = 21, H_ = 128, W_ = 128, P_ = 4096;
constexpr int T_ = 128;                  // tile size (p and q)
constexpr int NT = P_ / T_;              // 32 tiles per dim
constexpr int NTRI = NT * (NT + 1) / 2;  // 528 upper-tri tile pairs per n
constexpr int NBLK = NTRI * N_;          // 2112 energy blocks
constexpr float INV_RGB = 1.0f / 15.0f;
constexpr float INV_XY = 1.0f / 40.0f;   // 1/(SIGMA_XY*SCALE)
constexpr float SQRT_LOG2E = 1.2011224087864498f; // sqrt(log2(e))
constexpr float OUT_SCALE = -0.05f / 16384.0f;    // 0.1 * -0.5 / (N*P)

typedef _Float16 half8 __attribute__((ext_vector_type(8)));
typedef float floatx4 __attribute__((ext_vector_type(4)));

__global__ void __launch_bounds__(64) prep_kernel(
    const float* __restrict__ img, const float* __restrict__ seg,
    const float* __restrict__ roi, const float* __restrict__ lab,
    _Float16* __restrict__ comb, float* __restrict__ gate) {
  int idx = blockIdx.x * 64 + threadIdx.x; // n*P + p ; one wave == one (n,y) row
  int n = idx >> 12;
  int p = idx & (P_ - 1);
  int y = p >> 6, x = p & 63;
  int iy = 2 * y, ix = 2 * x;
  const size_t hw = (size_t)H_ * W_;

  float r = roi[(size_t)n * hw + iy * W_ + ix];
  float lb = lab[(size_t)n * hw + iy * W_ + ix];
  bool unlabeled = ((int)lb == 255);

  const float* sb = seg + (size_t)n * K_ * hw + (size_t)iy * W_ + ix;
  _Float16 ch[32];
  float mx = -1e30f;
#pragma unroll
  for (int k = 0; k < K_; k++) {
    const float* s = sb + (size_t)k * hw;
    float v = 0.25f * (s[0] + s[1] + s[W_] + s[W_ + 1]); // bilinear @0.5 == 2x2 avg
    mx = fmaxf(mx, v);
    ch[k] = (_Float16)(v * r); // seg_m = seg_s * roi, rounded to f16
  }
  ch[21] = (_Float16)0.0f; ch[22] = (_Float16)0.0f; ch[23] = (_Float16)0.0f;

  const float* ib = img + (size_t)n * 3 * hw + (size_t)iy * W_ + ix;
  ch[24] = (_Float16)((float)x * INV_XY * SQRT_LOG2E);
  ch[25] = (_Float16)((float)y * INV_XY * SQRT_LOG2E);
  ch[26] = (_Float16)(ib[0] * INV_RGB * SQRT_LOG2E);
  ch[27] = (_Float16)(ib[hw] * INV_RGB * SQRT_LOG2E);
  ch[28] = (_Float16)(ib[2 * hw] * INV_RGB * SQRT_LOG2E);

  // cs from the ROUNDED, pre-scaled channels: arg_diag = sum(ch^2) + 2*cs ~ 0.
  float sq = 0.0f;
#pragma unroll
  for (int j = 24; j < 29; j++) { float v = (float)ch[j]; sq = fmaf(v, v, sq); }
  ch[29] = (_Float16)(-0.5f * sq);
  ch[30] = (_Float16)1.0f;
  ch[31] = (_Float16)0.0f;

  float4* dst = (float4*)(comb + (size_t)idx * 32);
  const float4* src = (const float4*)ch;
#pragma unroll
  for (int j = 0; j < 4; j++) dst[j] = src[j];

  float g = unlabeled ? 1.0f : (r - mx);
  gate[idx] = fmaxf(g, 0.0f);
}

__global__ void __launch_bounds__(256, 4) energy_kernel(
    const _Float16* __restrict__ comb, const float* __restrict__ gate,
    float* __restrict__ partial) {
  // Decode upper-triangular tile pair (pb <= qb) from blockIdx.x in [0, 528).
  int t = blockIdx.x;
  int pb = 0;
  while (t >= NT - pb) { t -= NT - pb; pb++; }
  int qb = pb + t;
  int n = blockIdx.y;
  int tid = threadIdx.x;
  int lane = tid & 63, wave = tid >> 6;
  int m = lane & 15, quad = lane >> 4;

  const _Float16* combn = comb + (size_t)n * P_ * 32;
  const float* gaten = gate + (size_t)n * P_;
  const half8 zfrag = {};

  // A-side preload only (small): 2 p-strips + p-gates.
  half8 acomb[2], aseg0[2];
  float gpv[2][4];
#pragma unroll
  for (int s = 0; s < 2; s++) {
    int prow = pb * T_ + (2 * wave + s) * 16 + m;
    acomb[s] = *(const half8*)(combn + (size_t)prow * 32 + quad * 8);
    aseg0[s] = (quad == 3) ? zfrag : acomb[s]; // kill feat/cs channels for G
#pragma unroll
    for (int r = 0; r < 4; r++)
      gpv[s][r] = gaten[pb * T_ + (2 * wave + s) * 16 + quad * 4 + r];
  }

  const _Float16* qcomb = combn + (size_t)qb * T_ * 32; // wave-independent
  const float* qgate = gaten + qb * T_;
  bool patch = (quad == 3);

  // Fully unrolled (compile-time indices) but B-side STREAMED per iteration:
  // only ~2-3 fragments live at once -> VGPR <= 128 cap feasible.
  float acc = 0.0f;
#pragma unroll
  for (int qs = 0; qs < 8; qs++) {
    half8 b = *(const half8*)(qcomb + (size_t)(qs * 16 + m) * 32 + quad * 8);
    if (patch) {
      _Float16 cs = b[5];           // stored ch29 = cs(q)
      b[5] = (_Float16)1.0f;        // pairs with A's csp
      b[6] = cs;                    // pairs with A's 1.0
      b[7] = (_Float16)0.0f;
    }
    float gq = qgate[qs * 16 + m];
#pragma unroll
    for (int s = 0; s < 2; s++) {
      floatx4 C1 = {0.0f, 0.0f, 0.0f, 0.0f};
      floatx4 G = {0.0f, 0.0f, 0.0f, 0.0f};
      C1 = __builtin_amdgcn_mfma_f32_16x16x32_f16(acomb[s], b, C1, 0, 0, 0);
      G = __builtin_amdgcn_mfma_f32_16x16x32_f16(aseg0[s], b, G, 0, 0, 0);
#pragma unroll
      for (int r = 0; r < 4; r++) {
        float arg = C1[r] - G[r];              // = log2e*fp.fq + csp + csq
        float A = __builtin_amdgcn_exp2f(arg);
        A = fminf(A, 1.0f);
        acc = fmaf(A * G[r], gpv[s][r] + gq, acc);
      }
    }
  }

  // Reduce within block; store partial to a distinct address (no atomics).
#pragma unroll
  for (int off = 32; off > 0; off >>= 1) acc += __shfl_down(acc, off, 64);
  __shared__ float wsum[4];
  if (lane == 0) wsum[wave] = acc;
  __syncthreads();
  if (tid == 0) {
    float s = (wsum[0] + wsum[1]) + (wsum[2] + wsum[3]);
    float wb = (pb == qb) ? 0.5f : 1.0f;
    partial[blockIdx.y * NTRI + blockIdx.x] = s * wb;
  }
}

__global__ void __launch_bounds__(256) reduce_kernel(
    const float* __restrict__ partial, float* __restrict__ out) {
  int tid = threadIdx.x;
  float acc = 0.0f;
  for (int i = tid; i < NBLK; i += 256) acc += partial[i];
#pragma unroll
  for (int off = 32; off > 0; off >>= 1) acc += __shfl_down(acc, off, 64);
  __shared__ float wsum[4];
  int lane = tid & 63, wave = tid >> 6;
  if (lane == 0) wsum[wave] = acc;
  __syncthreads();
  if (tid == 0) {
    float s = (wsum[0] + wsum[1]) + (wsum[2] + wsum[3]);
    out[0] = s * OUT_SCALE;
  }
}

extern "C" void kernel_launch(void* const* d_in, const int* in_sizes, int n_in,
                              void* d_out, int out_size, void* d_ws, size_t ws_size,
                              hipStream_t stream) {
  const float* images = (const float*)d_in[0];
  const float* segs = (const float*)d_in[1];
  const float* rois = (const float*)d_in[2];
  const float* labels = (const float*)d_in[3];
  float* out = (float*)d_out;

  char* ws = (char*)d_ws;
  _Float16* comb = (_Float16*)ws;                                  // 1 MB
  float* gate = (float*)(ws + (size_t)N_ * P_ * 32 * 2);           // 64 KB
  float* partial = (float*)(ws + (size_t)N_ * P_ * 32 * 2 +
                            (size_t)N_ * P_ * sizeof(float));      // 8.25 KB

  prep_kernel<<<dim3(N_ * P_ / 64), dim3(64), 0, stream>>>(
      images, segs, rois, labels, comb, gate);
  energy_kernel<<<dim3(NTRI, N_), dim3(256), 0, stream>>>(comb, gate, partial);
  reduce_kernel<<<dim3(1), dim3(256), 0, stream>>>(partial, out);
}